// Round 1
// baseline (23.793 us; speedup 1.0000x reference)
//
#include <hip/hip_runtime.h>

// Problem: x [4096, 3072] fp32.
//   out = sum(G) - trace(G),  G = (x^2)(x^2)^T / D
//       = ( sum_d (colsum_d)^2  -  sum_{i,d} x^4 ) / D,   colsum_d = sum_i x[i,d]^2
// Single streaming pass + tiny reductions. Deterministic fixed-order trees, no atomics.

#define NROWS 4096
#define NCOLS 3072
#define NC4   (NCOLS / 4)        // 768 float4 columns
#define GX    3                  // NC4 / 256
#define NCHUNK 128               // row chunks
#define ROWS_PER (NROWS / NCHUNK) // 32
#define DINV  (1.0 / (double)NCOLS)

// ws layout (bytes):
//   [0,   96)                       double cs_part[12]      (k2 -> k3)
//   [128, 128 + NCHUNK*NCOLS*4)     float  col_part[NCHUNK][NCOLS]  (k1 -> k2)
//   [next, +NCHUNK*GX*4)            float  q_part[NCHUNK*GX]        (k1 -> k3)
#define WS_CS_OFF  0
#define WS_COL_OFF 128
#define WS_Q_OFF   (WS_COL_OFF + NCHUNK * NCOLS * 4)

__global__ __launch_bounds__(256) void k1_colsq(const float* __restrict__ x,
                                                float* __restrict__ col_part,
                                                float* __restrict__ q_part) {
    const int t  = threadIdx.x;
    const int c4 = blockIdx.x * 256 + t;        // 0..767
    const int r0 = blockIdx.y * ROWS_PER;
    const float4* __restrict__ x4 = (const float4*)x;

    float sx = 0.f, sy = 0.f, sz = 0.f, sw = 0.f;
    float q = 0.f;
    #pragma unroll 8
    for (int r = r0; r < r0 + ROWS_PER; ++r) {
        float4 v = x4[(size_t)r * NC4 + c4];
        float a = v.x * v.x, b = v.y * v.y, c = v.z * v.z, d = v.w * v.w;
        sx += a; sy += b; sz += c; sw += d;
        q += a * a; q += b * b; q += c * c; q += d * d;
    }
    float4 s = make_float4(sx, sy, sz, sw);
    ((float4*)col_part)[(size_t)blockIdx.y * NC4 + c4] = s;

    // block-reduce quartic partial (4 waves of 64)
    #pragma unroll
    for (int off = 32; off > 0; off >>= 1) q += __shfl_down(q, off);
    __shared__ float qs[4];
    if ((t & 63) == 0) qs[t >> 6] = q;
    __syncthreads();
    if (t == 0) q_part[blockIdx.y * GX + blockIdx.x] = (qs[0] + qs[1]) + (qs[2] + qs[3]);
}

__global__ __launch_bounds__(256) void k2_colreduce(const float* __restrict__ col_part,
                                                    double* __restrict__ cs_part) {
    const int t = threadIdx.x;
    const int d = blockIdx.x * 256 + t;         // 0..3071
    float s = 0.f;
    #pragma unroll 8
    for (int c = 0; c < NCHUNK; ++c) s += col_part[(size_t)c * NCOLS + d];
    double sq = (double)s * (double)s;
    #pragma unroll
    for (int off = 32; off > 0; off >>= 1) sq += __shfl_down(sq, off);
    __shared__ double ds[4];
    if ((t & 63) == 0) ds[t >> 6] = sq;
    __syncthreads();
    if (t == 0) cs_part[blockIdx.x] = (ds[0] + ds[1]) + (ds[2] + ds[3]);
}

__global__ __launch_bounds__(64) void k3_final(const double* __restrict__ cs_part,
                                               const float* __restrict__ q_part,
                                               float* __restrict__ out) {
    const int t = threadIdx.x;
    double acc = 0.0;
    for (int i = t; i < NCOLS / 256; i += 64) acc += cs_part[i];     // 12 terms
    for (int i = t; i < NCHUNK * GX; i += 64) acc -= (double)q_part[i]; // 384 terms
    #pragma unroll
    for (int off = 32; off > 0; off >>= 1) acc += __shfl_down(acc, off);
    if (t == 0) out[0] = (float)(acc * DINV);
}

extern "C" void kernel_launch(void* const* d_in, const int* in_sizes, int n_in,
                              void* d_out, int out_size, void* d_ws, size_t ws_size,
                              hipStream_t stream) {
    const float* x = (const float*)d_in[0];
    float* out = (float*)d_out;
    char* ws = (char*)d_ws;
    double* cs_part  = (double*)(ws + WS_CS_OFF);
    float*  col_part = (float*)(ws + WS_COL_OFF);
    float*  q_part   = (float*)(ws + WS_Q_OFF);

    k1_colsq<<<dim3(GX, NCHUNK), 256, 0, stream>>>(x, col_part, q_part);
    k2_colreduce<<<NCOLS / 256, 256, 0, stream>>>(col_part, cs_part);
    k3_final<<<1, 64, 0, stream>>>(cs_part, q_part, out);
}

// Round 2
// 21.777 us; speedup vs baseline: 1.0926x; 1.0926x over previous
//
#include <hip/hip_runtime.h>

// x [4096, 3072] fp32.
//   out = ( sum_d (colsum_d)^2 - sum x^4 ) / D,   colsum_d = sum_i x[i,d]^2
// k1: 768 blocks stream the 48 MiB input -> chunk column-partials + quartic partials.
// k2: 13 blocks reduce; last-arriving block (atomic counter) does the fixed-order
//     final combine -> deterministic, no third kernel.

#define NROWS 4096
#define NCOLS 3072
#define NC4   768                 // float4 columns
#define GX    3                   // NC4 / 256
#define NCHUNK 256                // row chunks
#define ROWS_PER 16               // NROWS / NCHUNK
#define DINV  (1.0 / (double)NCOLS)

// ws layout (bytes):
#define WS_CNT_OFF 0                              // uint counter
#define WS_CS_OFF  128                            // double cs_part[13]
#define WS_COL_OFF 512                            // float col_part[256][3072] = 3 MiB
#define WS_Q_OFF   (WS_COL_OFF + NCHUNK * NCOLS * 4)  // float q_part[768]

__global__ __launch_bounds__(256) void k1_colsq(const float* __restrict__ x,
                                                float* __restrict__ col_part,
                                                float* __restrict__ q_part,
                                                unsigned int* __restrict__ counter) {
    const int t  = threadIdx.x;
    const int c4 = blockIdx.x * 256 + t;          // 0..767
    const int r0 = blockIdx.y * ROWS_PER;
    const float4* __restrict__ x4 = (const float4*)x;

    if (t == 0 && blockIdx.x == 0 && blockIdx.y == 0) *counter = 0u;  // reset for k2

    float sx = 0.f, sy = 0.f, sz = 0.f, sw = 0.f, q = 0.f;
    #pragma unroll
    for (int i = 0; i < ROWS_PER; ++i) {
        float4 v = x4[(size_t)(r0 + i) * NC4 + c4];
        float a = v.x * v.x, b = v.y * v.y, c = v.z * v.z, d = v.w * v.w;
        sx += a; sy += b; sz += c; sw += d;
        q += a * a; q += b * b; q += c * c; q += d * d;
    }
    ((float4*)col_part)[(size_t)blockIdx.y * NC4 + c4] = make_float4(sx, sy, sz, sw);

    #pragma unroll
    for (int off = 32; off > 0; off >>= 1) q += __shfl_down(q, off);
    __shared__ float qs[4];
    if ((t & 63) == 0) qs[t >> 6] = q;
    __syncthreads();
    if (t == 0) q_part[blockIdx.y * GX + blockIdx.x] = (qs[0] + qs[1]) + (qs[2] + qs[3]);
}

__global__ __launch_bounds__(256) void k2_finish(const float* __restrict__ col_part,
                                                 const float* __restrict__ q_part,
                                                 double* __restrict__ cs_part,
                                                 unsigned int* __restrict__ counter,
                                                 float* __restrict__ out) {
    const int t = threadIdx.x;
    const int b = blockIdx.x;                     // 0..12
    const int lane = t & 63, w = t >> 6;
    __shared__ float4 ls[4][64];
    __shared__ double dsh[4];
    double partial = 0.0;

    if (b < 12) {
        // columns b*256 .. b*256+255 (as 64 float4 cols), chunks split 4-ways across waves
        const float4* __restrict__ cp4 = (const float4*)col_part;
        const int c4 = b * 64 + lane;
        float4 s = make_float4(0.f, 0.f, 0.f, 0.f);
        #pragma unroll 16
        for (int c = w * 64; c < w * 64 + 64; ++c) {
            float4 v = cp4[(size_t)c * NC4 + c4];
            s.x += v.x; s.y += v.y; s.z += v.z; s.w += v.w;
        }
        ls[w][lane] = s;
        __syncthreads();
        if (w == 0) {
            float4 a = ls[0][lane], bb = ls[1][lane], cc = ls[2][lane], dd = ls[3][lane];
            double cx = ((double)a.x + (double)bb.x) + ((double)cc.x + (double)dd.x);
            double cy = ((double)a.y + (double)bb.y) + ((double)cc.y + (double)dd.y);
            double cz = ((double)a.z + (double)bb.z) + ((double)cc.z + (double)dd.z);
            double cw = ((double)a.w + (double)bb.w) + ((double)cc.w + (double)dd.w);
            partial = (cx * cx + cy * cy) + (cz * cz + cw * cw);
            #pragma unroll
            for (int off = 32; off > 0; off >>= 1) partial += __shfl_down(partial, off);
        }
    } else {
        // quartic partials: 768 entries, 3 per thread
        double q = (double)q_part[t] + (double)q_part[t + 256] + (double)q_part[t + 512];
        #pragma unroll
        for (int off = 32; off > 0; off >>= 1) q += __shfl_down(q, off);
        if (lane == 0) dsh[w] = q;
        __syncthreads();
        if (t == 0) partial = (dsh[0] + dsh[1]) + (dsh[2] + dsh[3]);
    }

    if (t == 0) {
        __hip_atomic_store(&cs_part[b], partial, __ATOMIC_RELEASE, __HIP_MEMORY_SCOPE_AGENT);
        unsigned int old = __hip_atomic_fetch_add(counter, 1u, __ATOMIC_ACQ_REL,
                                                  __HIP_MEMORY_SCOPE_AGENT);
        if (old == 12u) {                         // last block: fixed-order combine
            double acc = 0.0;
            #pragma unroll
            for (int i = 0; i < 12; ++i)
                acc += __hip_atomic_load(&cs_part[i], __ATOMIC_ACQUIRE,
                                         __HIP_MEMORY_SCOPE_AGENT);
            acc -= __hip_atomic_load(&cs_part[12], __ATOMIC_ACQUIRE,
                                     __HIP_MEMORY_SCOPE_AGENT);
            out[0] = (float)(acc * DINV);
        }
    }
}

extern "C" void kernel_launch(void* const* d_in, const int* in_sizes, int n_in,
                              void* d_out, int out_size, void* d_ws, size_t ws_size,
                              hipStream_t stream) {
    const float* x = (const float*)d_in[0];
    float* out = (float*)d_out;
    char* ws = (char*)d_ws;
    unsigned int* counter = (unsigned int*)(ws + WS_CNT_OFF);
    double* cs_part  = (double*)(ws + WS_CS_OFF);
    float*  col_part = (float*)(ws + WS_COL_OFF);
    float*  q_part   = (float*)(ws + WS_Q_OFF);

    k1_colsq<<<dim3(GX, NCHUNK), 256, 0, stream>>>(x, col_part, q_part, counter);
    k2_finish<<<13, 256, 0, stream>>>(col_part, q_part, cs_part, counter, out);
}